// Round 1
// baseline (3910.618 us; speedup 1.0000x reference)
//
#include <hip/hip_runtime.h>
#include <hip/hip_bf16.h>
#include <stdint.h>

// Autoregressive LSTM decode, B=4096, H=1024, A=128, 50 steps.
// steps>=1: x==h  =>  gates = h @ (w_ih+w_hh)^T + bias.
// bf16 MFMA GEMM (fp32 accum), fp32 cell state c, fused cell epilogue.

#define B_SZ   4096
#define H_SZ   1024
#define A_SZ   128
#define NSTEP  50

using bf16 = __hip_bfloat16;
typedef __attribute__((ext_vector_type(8))) short bf16x8;   // 8 bf16 = 4 VGPR
typedef __attribute__((ext_vector_type(4))) float f32x4;    // MFMA C/D frag

__device__ __forceinline__ void gload_lds16(const void* gsrc, void* ldst) {
    // async global->LDS, 16B per lane; LDS dest = uniform base + lane*16
    __builtin_amdgcn_global_load_lds(
        (const __attribute__((address_space(1))) unsigned int*)gsrc,
        (__attribute__((address_space(3))) unsigned int*)ldst, 16, 0, 0);
}

__device__ __forceinline__ float sigf(float x) {
    return 1.f / (1.f + __expf(-x));
}
__device__ __forceinline__ float tanh_(float x) {
    float e = __expf(-2.f * fabsf(x));
    float t = (1.f - e) / (1.f + e);
    return copysignf(t, x);
}

// ---------------- prep kernels (run once per launch) ----------------

__global__ void prep_weights(const float4* __restrict__ wih,
                             const float4* __restrict__ whh,
                             bf16* __restrict__ Wc, bf16* __restrict__ Wi) {
    int i = blockIdx.x * 256 + threadIdx.x;     // over 4H*H/4 = 1048576
    float4 a = wih[i], b = whh[i];
    bf16 tc[4] = {__float2bfloat16(a.x + b.x), __float2bfloat16(a.y + b.y),
                  __float2bfloat16(a.z + b.z), __float2bfloat16(a.w + b.w)};
    bf16 ti[4] = {__float2bfloat16(a.x), __float2bfloat16(a.y),
                  __float2bfloat16(a.z), __float2bfloat16(a.w)};
    *(uint64_t*)(Wc + 4 * (size_t)i) = *(const uint64_t*)tc;
    *(uint64_t*)(Wi + 4 * (size_t)i) = *(const uint64_t*)ti;
}

__global__ void prep_cast(const float4* __restrict__ in, bf16* __restrict__ out) {
    int i = blockIdx.x * 256 + threadIdx.x;
    float4 a = in[i];
    bf16 t[4] = {__float2bfloat16(a.x), __float2bfloat16(a.y),
                 __float2bfloat16(a.z), __float2bfloat16(a.w)};
    *(uint64_t*)(out + 4 * (size_t)i) = *(const uint64_t*)t;
}

__global__ void prep_bias(const float* __restrict__ a, const float* __restrict__ b,
                          float* __restrict__ o) {
    int i = blockIdx.x * 256 + threadIdx.x;     // 4096
    o[i] = a[i] + b[i];
}

// ---------------- fused gates GEMM + LSTM cell ----------------
// grid: (H/32, B/128).  Block computes 128 batch rows x 32 j-cols, all 4 gates.
// LDS: A tile [128][64] bf16 (linear), B tile [4*32][64] bf16 (linear).
// 4 waves, 2x2: wave covers 64 rows x 16 j.  acc[gate][mfrag] = f32x4.

__global__ __launch_bounds__(256)
void lstm_gates(const bf16* __restrict__ hin, const bf16* __restrict__ W,
                const float* __restrict__ bias, float* __restrict__ c,
                bf16* __restrict__ hout, int step0) {
    __shared__ __align__(16) bf16 lA[128 * 64];   // 16 KB
    __shared__ __align__(16) bf16 lB[128 * 64];   // 16 KB (4 gates x 32 rows)

    const int tid  = threadIdx.x;
    const int w    = tid >> 6;
    const int lane = tid & 63;
    const int wr   = w >> 1;           // 0..1 (m half)
    const int wc   = w & 1;            // 0..1 (j half)
    const int bm0  = blockIdx.y * 128;
    const int j0   = blockIdx.x * 32;

    f32x4 acc[4][4];                   // [gate][m-frag]
    const f32x4 z = {0.f, 0.f, 0.f, 0.f};
#pragma unroll
    for (int g = 0; g < 4; ++g)
#pragma unroll
        for (int m = 0; m < 4; ++m) acc[g][m] = z;

    const int lrow = lane >> 3;          // 0..7
    const int lcol = (lane & 7) * 16;    // byte offset within 128B row
    const char* hin_b = (const char*)hin;
    const char* W_b   = (const char*)W;

    for (int k0 = 0; k0 < H_SZ; k0 += 64) {
        __syncthreads();   // previous tile's reads done before overwrite
        // ---- stage A (h tile) and B (4 gate weight tiles), 16B/lane async
#pragma unroll
        for (int q = 0; q < 4; ++q) {
            int chunk = w * 4 + q;                 // 0..15
            int row   = chunk * 8 + lrow;          // 0..127
            const void* ga = hin_b + ((size_t)(bm0 + row) * H_SZ + k0) * 2 + lcol;
            gload_lds16(ga, (void*)(lA + chunk * 512));
            int g  = row >> 5;                     // gate 0..3
            int jr = row & 31;                     // 0..31
            size_t n = (size_t)g * H_SZ + j0 + jr; // W row
            const void* gb = W_b + (n * H_SZ + k0) * 2 + lcol;
            gload_lds16(gb, (void*)(lB + chunk * 512));
        }
        __syncthreads();   // compiler drains vmcnt before barrier

        // ---- compute: 2 sub-steps of K=32
#pragma unroll
        for (int kk = 0; kk < 2; ++kk) {
            bf16x8 af[4];
#pragma unroll
            for (int m = 0; m < 4; ++m)
                af[m] = *(const bf16x8*)(lA + (wr * 64 + m * 16 + (lane & 15)) * 64
                                            + kk * 32 + (lane >> 4) * 8);
#pragma unroll
            for (int g = 0; g < 4; ++g) {
                bf16x8 bfr = *(const bf16x8*)(lB + (g * 32 + wc * 16 + (lane & 15)) * 64
                                                 + kk * 32 + (lane >> 4) * 8);
#pragma unroll
                for (int m = 0; m < 4; ++m)
                    acc[g][m] = __builtin_amdgcn_mfma_f32_16x16x32_bf16(
                        af[m], bfr, acc[g][m], 0, 0, 0);
            }
        }
    }

    // ---- fused LSTM cell epilogue (per-lane: i/f/g/o share (row,col))
    const int jc = j0 + wc * 16 + (lane & 15);
    const float bi = bias[jc];
    const float bf_ = bias[H_SZ + jc];
    const float bg = bias[2 * H_SZ + jc];
    const float bo = bias[3 * H_SZ + jc];
#pragma unroll
    for (int m = 0; m < 4; ++m) {
#pragma unroll
        for (int r = 0; r < 4; ++r) {
            int row = bm0 + wr * 64 + m * 16 + (lane >> 4) * 4 + r;
            size_t idx = (size_t)row * H_SZ + jc;
            float iv = acc[0][m][r] + bi;
            float fv = acc[1][m][r] + bf_;
            float gv = acc[2][m][r] + bg;
            float ov = acc[3][m][r] + bo;
            float cp = step0 ? 0.f : c[idx];
            float cn = sigf(fv) * cp + sigf(iv) * tanh_(gv);
            float hn = sigf(ov) * tanh_(cn);
            c[idx] = cn;
            hout[idx] = __float2bfloat16(hn);
        }
    }
}

// ---------------- prediction GEMM: out = h @ w_pred^T + b_pred ----------------
// grid: B/64 blocks. Block: 64 rows x 128 cols (all of A). 4 waves, wave w: cols w*32..+31.

__global__ __launch_bounds__(256)
void pred_kernel(const bf16* __restrict__ h, const bf16* __restrict__ wp,
                 const float* __restrict__ bp, float* __restrict__ out) {
    __shared__ __align__(16) bf16 lH[64 * 64];    // 8 KB
    __shared__ __align__(16) bf16 lP[128 * 64];   // 16 KB

    const int tid  = threadIdx.x;
    const int w    = tid >> 6;
    const int lane = tid & 63;
    const int bm0  = blockIdx.x * 64;

    f32x4 acc[4][2];                  // [m-frag][n-frag]
    const f32x4 z = {0.f, 0.f, 0.f, 0.f};
#pragma unroll
    for (int m = 0; m < 4; ++m)
#pragma unroll
        for (int n = 0; n < 2; ++n) acc[m][n] = z;

    const int lrow = lane >> 3;
    const int lcol = (lane & 7) * 16;
    const char* h_b  = (const char*)h;
    const char* wp_b = (const char*)wp;

    for (int k0 = 0; k0 < H_SZ; k0 += 64) {
        __syncthreads();
#pragma unroll
        for (int q = 0; q < 2; ++q) {             // A: 8 chunks total
            int chunk = w * 2 + q;                // 0..7
            int row   = chunk * 8 + lrow;         // 0..63
            const void* ga = h_b + ((size_t)(bm0 + row) * H_SZ + k0) * 2 + lcol;
            gload_lds16(ga, (void*)(lH + chunk * 512));
        }
#pragma unroll
        for (int q = 0; q < 4; ++q) {             // B: 16 chunks total
            int chunk = w * 4 + q;                // 0..15
            int row   = chunk * 8 + lrow;         // 0..127 (w_pred row)
            const void* gb = wp_b + ((size_t)row * H_SZ + k0) * 2 + lcol;
            gload_lds16(gb, (void*)(lP + chunk * 512));
        }
        __syncthreads();

#pragma unroll
        for (int kk = 0; kk < 2; ++kk) {
            bf16x8 af[4];
#pragma unroll
            for (int m = 0; m < 4; ++m)
                af[m] = *(const bf16x8*)(lH + (m * 16 + (lane & 15)) * 64
                                            + kk * 32 + (lane >> 4) * 8);
#pragma unroll
            for (int n = 0; n < 2; ++n) {
                bf16x8 bfr = *(const bf16x8*)(lP + (w * 32 + n * 16 + (lane & 15)) * 64
                                                 + kk * 32 + (lane >> 4) * 8);
#pragma unroll
                for (int m = 0; m < 4; ++m)
                    acc[m][n] = __builtin_amdgcn_mfma_f32_16x16x32_bf16(
                        af[m], bfr, acc[m][n], 0, 0, 0);
            }
        }
    }

#pragma unroll
    for (int m = 0; m < 4; ++m)
#pragma unroll
        for (int n = 0; n < 2; ++n)
#pragma unroll
            for (int r = 0; r < 4; ++r) {
                int row = bm0 + m * 16 + (lane >> 4) * 4 + r;
                int col = w * 32 + n * 16 + (lane & 15);
                out[(size_t)row * A_SZ + col] = acc[m][n][r] + bp[col];
            }
}

// ---------------- launcher ----------------

extern "C" void kernel_launch(void* const* d_in, const int* in_sizes, int n_in,
                              void* d_out, int out_size, void* d_ws, size_t ws_size,
                              hipStream_t stream) {
    const float* enc   = (const float*)d_in[0];   // (1,B,H)
    const float* wih   = (const float*)d_in[1];   // (4H,H)
    const float* whh   = (const float*)d_in[2];   // (4H,H)
    const float* bih   = (const float*)d_in[3];   // (4H)
    const float* bhh   = (const float*)d_in[4];   // (4H)
    const float* wpred = (const float*)d_in[5];   // (A,H)
    const float* bpred = (const float*)d_in[6];   // (A)
    float* out = (float*)d_out;

    char* ws = (char*)d_ws;
    const size_t WH  = (size_t)4 * H_SZ * H_SZ;   // 4H*H elements
    const size_t BH  = (size_t)B_SZ * H_SZ;
    bf16*  Wc   = (bf16*)ws;                 ws += WH * 2;          // 8 MB
    bf16*  Wi   = (bf16*)ws;                 ws += WH * 2;          // 8 MB
    bf16*  h0   = (bf16*)ws;                 ws += BH * 2;          // 8 MB
    bf16*  h1   = (bf16*)ws;                 ws += BH * 2;          // 8 MB
    float* cbuf = (float*)ws;                ws += BH * 4;          // 16 MB
    bf16*  wp   = (bf16*)ws;                 ws += (size_t)A_SZ * H_SZ * 2; // 256 KB
    float* bias = (float*)ws;                ws += 4 * H_SZ * 4;    // 16 KB

    // prep (once per launch)
    prep_weights<<<4096, 256, 0, stream>>>((const float4*)wih, (const float4*)whh, Wc, Wi);
    prep_cast<<<128, 256, 0, stream>>>((const float4*)wpred, wp);
    prep_bias<<<16, 256, 0, stream>>>(bih, bhh, bias);
    prep_cast<<<4096, 256, 0, stream>>>((const float4*)enc, h0);   // x0 -> bf16

    bf16* hbuf[2] = {h0, h1};
    for (int s = 0; s < NSTEP; ++s) {
        const bf16* hin = hbuf[s & 1];
        bf16* hout      = hbuf[(s + 1) & 1];
        lstm_gates<<<dim3(H_SZ / 32, B_SZ / 128), 256, 0, stream>>>(
            hin, (s == 0) ? Wi : Wc, bias, cbuf, hout, s == 0 ? 1 : 0);
        pred_kernel<<<B_SZ / 64, 256, 0, stream>>>(
            hout, wp, bpred, out + (size_t)s * B_SZ * A_SZ);
    }
}

// Round 2
// 2671.322 us; speedup vs baseline: 1.4639x; 1.4639x over previous
//
#include <hip/hip_runtime.h>
#include <hip/hip_bf16.h>
#include <stdint.h>

// Autoregressive LSTM decode, B=4096, H=1024, A=128, 50 steps.
// steps>=1: x==h  =>  gates = h @ (w_ih+w_hh)^T + bias.
// Gates GEMM: 256^2-tile 8-phase schedule (T1+T2+T3+T4+T5), fused LSTM cell.

#define B_SZ   4096
#define H_SZ   1024
#define A_SZ   128
#define NSTEP  50
#define NT     16      // K tiles of 64 (K = 1024)

using bf16 = __hip_bfloat16;
typedef __attribute__((ext_vector_type(8))) short bf16x8;   // 8 bf16 = 4 VGPR
typedef __attribute__((ext_vector_type(4))) float f32x4;    // MFMA C/D frag

__device__ __forceinline__ void gload_lds16(const void* g, void* l) {
    __builtin_amdgcn_global_load_lds(
        (const __attribute__((address_space(1))) unsigned int*)g,
        (__attribute__((address_space(3))) unsigned int*)l, 16, 0, 0);
}

#define FENCE() asm volatile("" ::: "memory")
#define BAR()   do { FENCE(); __builtin_amdgcn_s_barrier(); FENCE(); } while (0)
#define VMC6()  asm volatile("s_waitcnt vmcnt(6)" ::: "memory")
#define VMC0()  asm volatile("s_waitcnt vmcnt(0)" ::: "memory")
#define LGKM0() asm volatile("s_waitcnt lgkmcnt(0)" ::: "memory")

__device__ __forceinline__ float sigf(float x) {
    return 1.f / (1.f + __expf(-x));
}
__device__ __forceinline__ float tanh_(float x) {
    float e = __expf(-2.f * fabsf(x));
    float t = (1.f - e) / (1.f + e);
    return copysignf(t, x);
}

// ---------------- prep kernels (run once per launch) ----------------

__global__ void prep_weights(const float4* __restrict__ wih,
                             const float4* __restrict__ whh,
                             bf16* __restrict__ Wc, bf16* __restrict__ Wi) {
    int i = blockIdx.x * 256 + threadIdx.x;
    float4 a = wih[i], b = whh[i];
    bf16 tc[4] = {__float2bfloat16(a.x + b.x), __float2bfloat16(a.y + b.y),
                  __float2bfloat16(a.z + b.z), __float2bfloat16(a.w + b.w)};
    bf16 ti[4] = {__float2bfloat16(a.x), __float2bfloat16(a.y),
                  __float2bfloat16(a.z), __float2bfloat16(a.w)};
    *(uint64_t*)(Wc + 4 * (size_t)i) = *(const uint64_t*)tc;
    *(uint64_t*)(Wi + 4 * (size_t)i) = *(const uint64_t*)ti;
}

__global__ void prep_cast(const float4* __restrict__ in, bf16* __restrict__ out) {
    int i = blockIdx.x * 256 + threadIdx.x;
    float4 a = in[i];
    bf16 t[4] = {__float2bfloat16(a.x), __float2bfloat16(a.y),
                 __float2bfloat16(a.z), __float2bfloat16(a.w)};
    *(uint64_t*)(out + 4 * (size_t)i) = *(const uint64_t*)t;
}

__global__ void prep_bias(const float* __restrict__ a, const float* __restrict__ b,
                          float* __restrict__ o) {
    int i = blockIdx.x * 256 + threadIdx.x;
    o[i] = a[i] + b[i];
}

// ---------------- fused gates GEMM + LSTM cell, 256^2 8-phase ----------------
// grid: 256 blocks (1/CU, XCD-swizzled). Block: 256 batch rows x (4 gates x 64 j).
// 8 waves 2Mx4N; wave = 128 rows x (4 gates x 16 j); acc[8 m][4 gates].
// LDS: A[2][256][64] + B[2][256][64] bf16 = 128 KiB, st-swizzled via global src.
// Per K-tile: 4 phases {p0: m0-3 x n0-1 (reads A8+B4), p1: m0-3 x n2-3 (B4),
// p2: m4-7 x n0-1 (A8), p3: m4-7 x n2-3 (0)}; 1 half-tile staged per phase;
// vmcnt(6) once per K-tile boundary (3 half-tiles in flight).

__global__ __launch_bounds__(512, 2)
void lstm_gates(const bf16* __restrict__ hin, const bf16* __restrict__ W,
                const float* __restrict__ bias, float* __restrict__ c,
                bf16* __restrict__ hout, int step0) {
    __shared__ __align__(16) bf16 sm[65536];          // 128 KiB
    bf16* const lA0 = sm;
    bf16* const lA1 = sm + 16384;
    bf16* const lB0 = sm + 32768;
    bf16* const lB1 = sm + 49152;

    const int tid  = threadIdx.x;
    const int w    = tid >> 6;
    const int lane = tid & 63;
    const int wr   = w >> 2;                 // 0..1
    const int wc   = w & 3;                  // 0..3

    const int bid     = blockIdx.x;
    const int logical = (bid & 7) * 32 + (bid >> 3);   // bijective XCD swizzle
    const int bm0     = (logical >> 4) * 256;
    const int j0      = (logical & 15) * 64;

    // write-side swizzle: global col byte for this thread's linear LDS slot
    const int scolb = ((tid & 7) * 16) ^ (((tid >> 3) & 7) << 4);
    const char* baseA = (const char*)hin + (size_t)(bm0 + (tid >> 3)) * 2048 + scolb;
    const char* baseB = (const char*)W   + (size_t)(j0  + (tid >> 3)) * 2048 + scolb;

    // read-side swizzled k-offsets (elements), kk=0/1
    const int cs0 = ((      (lane >> 4) * 16) ^ ((lane & 7) << 4)) >> 1;
    const int cs1 = ((64 + (lane >> 4) * 16) ^ ((lane & 7) << 4)) >> 1;
    const int rA  = (wr * 128 + (lane & 15)) * 64;     // element offset of A row
    const int rB  = (wc * 16  + (lane & 15)) * 64;     // element offset of B row

    f32x4 acc[8][4];
    const f32x4 z = {0.f, 0.f, 0.f, 0.f};
#pragma unroll
    for (int m = 0; m < 8; ++m)
#pragma unroll
        for (int n = 0; n < 4; ++n) acc[m][n] = z;

    // stage one half-tile (128 rows x 64 k): 2 loads/thread, stream-ordered
    auto SGA = [&](int t, int h) {
        bf16* dst = ((t & 1) ? lA1 : lA0) + h * 8192 + w * 512;
        const char* g = baseA + (size_t)(h * 128) * 2048 + (size_t)t * 128;
        gload_lds16(g, dst);                          // q=0: rows h*128+0..63
        gload_lds16(g + (size_t)64 * 2048, dst + 4096); // q=1: rows +64
    };
    auto SGB = [&](int t, int h) {
        bf16* dst = ((t & 1) ? lB1 : lB0) + h * 8192 + w * 512;
        const char* g = baseB + (size_t)(h * 2) * 2097152 + (size_t)t * 128;
        gload_lds16(g, dst);                          // gate h*2
        gload_lds16(g + 2097152, dst + 4096);         // gate h*2+1
    };

    // prologue: stream order B0(0),B1(0),A0(0),A1(0),B0(1),B1(1),A0(1)
    SGB(0, 0); SGB(0, 1); SGA(0, 0); SGA(0, 1);
    SGB(1, 0); SGB(1, 1); SGA(1, 0);
    VMC6();      // tile 0 fully landed (3 half-tiles of tile 1 in flight)
    BAR();

    for (int t = 0; t < NT; ++t) {
        const bf16* Ad = (t & 1) ? lA1 : lA0;
        const bf16* Bd = (t & 1) ? lB1 : lB0;
        bf16x8 av[4][2], bv[4][2];

        // ---- phase 0: m0-3 x n0-1 (12 ds_reads); stage A1(t+1)
#pragma unroll
        for (int m = 0; m < 4; ++m) {
            av[m][0] = *(const bf16x8*)(Ad + rA + m * 1024 + cs0);
            av[m][1] = *(const bf16x8*)(Ad + rA + m * 1024 + cs1);
        }
#pragma unroll
        for (int n = 0; n < 2; ++n) {
            bv[n][0] = *(const bf16x8*)(Bd + rB + n * 4096 + cs0);
            bv[n][1] = *(const bf16x8*)(Bd + rB + n * 4096 + cs1);
        }
        if (t + 1 < NT) SGA(t + 1, 1);
        BAR(); LGKM0();
        __builtin_amdgcn_s_setprio(1);
#pragma unroll
        for (int n = 0; n < 2; ++n)
#pragma unroll
            for (int m = 0; m < 4; ++m) {
                acc[m][n] = __builtin_amdgcn_mfma_f32_16x16x32_bf16(av[m][0], bv[n][0], acc[m][n], 0, 0, 0);
                acc[m][n] = __builtin_amdgcn_mfma_f32_16x16x32_bf16(av[m][1], bv[n][1], acc[m][n], 0, 0, 0);
            }
        __builtin_amdgcn_s_setprio(0);
        BAR();

        // ---- phase 1: m0-3 x n2-3 (4 ds_reads); stage B0(t+2)
#pragma unroll
        for (int n = 2; n < 4; ++n) {
            bv[n][0] = *(const bf16x8*)(Bd + rB + n * 4096 + cs0);
            bv[n][1] = *(const bf16x8*)(Bd + rB + n * 4096 + cs1);
        }
        if (t + 2 < NT) SGB(t + 2, 0);
        BAR(); LGKM0();
        __builtin_amdgcn_s_setprio(1);
#pragma unroll
        for (int n = 2; n < 4; ++n)
#pragma unroll
            for (int m = 0; m < 4; ++m) {
                acc[m][n] = __builtin_amdgcn_mfma_f32_16x16x32_bf16(av[m][0], bv[n][0], acc[m][n], 0, 0, 0);
                acc[m][n] = __builtin_amdgcn_mfma_f32_16x16x32_bf16(av[m][1], bv[n][1], acc[m][n], 0, 0, 0);
            }
        __builtin_amdgcn_s_setprio(0);
        BAR();

        // ---- phase 2: m4-7 x n0-1 (8 ds_reads); stage B1(t+2)
#pragma unroll
        for (int m = 0; m < 4; ++m) {
            av[m][0] = *(const bf16x8*)(Ad + rA + (m + 4) * 1024 + cs0);
            av[m][1] = *(const bf16x8*)(Ad + rA + (m + 4) * 1024 + cs1);
        }
        if (t + 2 < NT) SGB(t + 2, 1);
        BAR(); LGKM0();
        __builtin_amdgcn_s_setprio(1);
#pragma unroll
        for (int n = 0; n < 2; ++n)
#pragma unroll
            for (int m = 0; m < 4; ++m) {
                acc[m + 4][n] = __builtin_amdgcn_mfma_f32_16x16x32_bf16(av[m][0], bv[n][0], acc[m + 4][n], 0, 0, 0);
                acc[m + 4][n] = __builtin_amdgcn_mfma_f32_16x16x32_bf16(av[m][1], bv[n][1], acc[m + 4][n], 0, 0, 0);
            }
        __builtin_amdgcn_s_setprio(0);
        BAR();

        // ---- phase 3: m4-7 x n2-3 (0 ds_reads); stage A0(t+2)
        if (t + 2 < NT) SGA(t + 2, 0);
        BAR(); LGKM0();
        __builtin_amdgcn_s_setprio(1);
#pragma unroll
        for (int n = 2; n < 4; ++n)
#pragma unroll
            for (int m = 0; m < 4; ++m) {
                acc[m + 4][n] = __builtin_amdgcn_mfma_f32_16x16x32_bf16(av[m][0], bv[n][0], acc[m + 4][n], 0, 0, 0);
                acc[m + 4][n] = __builtin_amdgcn_mfma_f32_16x16x32_bf16(av[m][1], bv[n][1], acc[m + 4][n], 0, 0, 0);
            }
        __builtin_amdgcn_s_setprio(0);
        // K-tile boundary: next tile's data must be landed (3 half-tiles stay in flight)
        if (t < NT - 1) {
            if (t == NT - 2) { VMC0(); } else { VMC6(); }
        }
        BAR();
    }

    // ---- fused LSTM cell epilogue (i/f/g/o lane-local: n-frag == gate)
    const int jc = j0 + wc * 16 + (lane & 15);
    const float bi  = bias[jc];
    const float bff = bias[H_SZ + jc];
    const float bg  = bias[2 * H_SZ + jc];
    const float bo  = bias[3 * H_SZ + jc];
#pragma unroll
    for (int m = 0; m < 8; ++m) {
#pragma unroll
        for (int r = 0; r < 4; ++r) {
            int row = bm0 + wr * 128 + m * 16 + (lane >> 4) * 4 + r;
            size_t idx = (size_t)row * H_SZ + jc;
            float iv = acc[m][0][r] + bi;
            float fv = acc[m][1][r] + bff;
            float gv = acc[m][2][r] + bg;
            float ov = acc[m][3][r] + bo;
            float cp = step0 ? 0.f : c[idx];
            float cn = sigf(fv) * cp + sigf(iv) * tanh_(gv);
            float hn = sigf(ov) * tanh_(cn);
            c[idx] = cn;
            hout[idx] = __float2bfloat16(hn);
        }
    }
}

// ---------------- prediction GEMM: out = h @ w_pred^T + b_pred ----------------
// grid: B/16 = 256 blocks (full-chip). Block: 16 rows x 128 cols, 4 waves.

__global__ __launch_bounds__(256)
void pred_kernel(const bf16* __restrict__ h, const bf16* __restrict__ wp,
                 const float* __restrict__ bp, float* __restrict__ out) {
    __shared__ __align__(16) bf16 lH[16 * 64];      // 2 KB
    __shared__ __align__(16) bf16 lP[128 * 64];     // 16 KB

    const int tid  = threadIdx.x;
    const int w    = tid >> 6;
    const int lane = tid & 63;
    const int bm0  = blockIdx.x * 16;

    const int scolb = ((tid & 7) * 16) ^ (((tid >> 3) & 7) << 4);
    const int cs0 = ((      (lane >> 4) * 16) ^ ((lane & 7) << 4)) >> 1;
    const int cs1 = ((64 + (lane >> 4) * 16) ^ ((lane & 7) << 4)) >> 1;

    f32x4 acc[2];
    const f32x4 z = {0.f, 0.f, 0.f, 0.f};
    acc[0] = z; acc[1] = z;

    const char* hb = (const char*)h  + (size_t)(bm0 + (tid >> 3)) * 2048 + scolb;
    const char* pb = (const char*)wp + (size_t)(tid >> 3) * 2048 + scolb;

    for (int t = 0; t < NT; ++t) {
        __syncthreads();
        if (tid < 128)
            gload_lds16(hb + (size_t)t * 128, lH + w * 512);
#pragma unroll
        for (int q = 0; q < 4; ++q)
            gload_lds16(pb + (size_t)(q * 32) * 2048 + (size_t)t * 128,
                        lP + (q * 4 + w) * 512);
        __syncthreads();

        bf16x8 a0 = *(const bf16x8*)(lH + (lane & 15) * 64 + cs0);
        bf16x8 a1 = *(const bf16x8*)(lH + (lane & 15) * 64 + cs1);
#pragma unroll
        for (int n = 0; n < 2; ++n) {
            int rowb = (w * 32 + n * 16 + (lane & 15)) * 64;
            bf16x8 b0 = *(const bf16x8*)(lP + rowb + cs0);
            bf16x8 b1 = *(const bf16x8*)(lP + rowb + cs1);
            acc[n] = __builtin_amdgcn_mfma_f32_16x16x32_bf16(a0, b0, acc[n], 0, 0, 0);
            acc[n] = __builtin_amdgcn_mfma_f32_16x16x32_bf16(a1, b1, acc[n], 0, 0, 0);
        }
    }

#pragma unroll
    for (int n = 0; n < 2; ++n)
#pragma unroll
        for (int r = 0; r < 4; ++r) {
            int row = bm0 + (lane >> 4) * 4 + r;
            int col = w * 32 + n * 16 + (lane & 15);
            out[(size_t)row * A_SZ + col] = acc[n][r] + bp[col];
        }
}

// ---------------- launcher ----------------

extern "C" void kernel_launch(void* const* d_in, const int* in_sizes, int n_in,
                              void* d_out, int out_size, void* d_ws, size_t ws_size,
                              hipStream_t stream) {
    const float* enc   = (const float*)d_in[0];   // (1,B,H)
    const float* wih   = (const float*)d_in[1];   // (4H,H)
    const float* whh   = (const float*)d_in[2];   // (4H,H)
    const float* bih   = (const float*)d_in[3];   // (4H)
    const float* bhh   = (const float*)d_in[4];   // (4H)
    const float* wpred = (const float*)d_in[5];   // (A,H)
    const float* bpred = (const float*)d_in[6];   // (A)
    float* out = (float*)d_out;

    char* ws = (char*)d_ws;
    const size_t WH = (size_t)4 * H_SZ * H_SZ;
    const size_t BH = (size_t)B_SZ * H_SZ;
    bf16*  Wc   = (bf16*)ws;                 ws += WH * 2;
    bf16*  Wi   = (bf16*)ws;                 ws += WH * 2;
    bf16*  h0   = (bf16*)ws;                 ws += BH * 2;
    bf16*  h1   = (bf16*)ws;                 ws += BH * 2;
    float* cbuf = (float*)ws;                ws += BH * 4;
    bf16*  wp   = (bf16*)ws;                 ws += (size_t)A_SZ * H_SZ * 2;
    float* bias = (float*)ws;                ws += 4 * H_SZ * 4;

    prep_weights<<<4096, 256, 0, stream>>>((const float4*)wih, (const float4*)whh, Wc, Wi);
    prep_cast<<<128, 256, 0, stream>>>((const float4*)wpred, wp);
    prep_bias<<<16, 256, 0, stream>>>(bih, bhh, bias);
    prep_cast<<<4096, 256, 0, stream>>>((const float4*)enc, h0);

    bf16* hbuf[2] = {h0, h1};
    for (int s = 0; s < NSTEP; ++s) {
        const bf16* hin = hbuf[s & 1];
        bf16* hout      = hbuf[(s + 1) & 1];
        lstm_gates<<<256, 512, 0, stream>>>(
            hin, (s == 0) ? Wi : Wc, bias, cbuf, hout, s == 0 ? 1 : 0);
        pred_kernel<<<256, 256, 0, stream>>>(
            hout, wp, bpred, out + (size_t)s * B_SZ * A_SZ);
    }
}